// Round 8
// baseline (88.415 us; speedup 1.0000x reference)
//
#include <hip/hip_runtime.h>
#include <math.h>

#define INV_TWO_PI 0.15915494309189535f
#define PPB 4  // points per block

// ---------------------------------------------------------------------------
// fast atan2: degree-15 odd minimax on [0,1] + quadrant fixup.
// Branch-cut semantics match numpy: atan2(+-0, neg) = +-pi, atan2(0,0)=0.
// ---------------------------------------------------------------------------
__device__ __forceinline__ float fast_atan2f(float y, float x) {
    const float PI   = 3.14159265358979f;
    const float PI_2 = 1.57079632679490f;
    float ax = fabsf(x), ay = fabsf(y);
    float mx = fmaxf(ax, ay), mn = fminf(ax, ay);
    float inv = __builtin_amdgcn_rcpf(mx);
    float t = (mx > 0.f) ? mn * inv : 0.f;   // guard 0/0
    float s = t * t;
    float r = -0.0040540580f;
    r = fmaf(r, s, 0.0218612288f);
    r = fmaf(r, s, -0.0559098861f);
    r = fmaf(r, s, 0.0964200441f);
    r = fmaf(r, s, -0.1390853351f);
    r = fmaf(r, s, 0.1994653599f);
    r = fmaf(r, s, -0.3332985605f);
    r = fmaf(r, s, 0.9999993329f);
    r = r * t;
    if (ay > ax) r = PI_2 - r;
    if (x < 0.f) r = PI - r;
    return copysignf(r, y);
}

// det = a.(b x c) computed directly so p == vertex gives det = 0, den = 0
// exactly (matches numpy reference; verified absmax == 0.0 in rounds 3/6/7).
__device__ __forceinline__ float solid_angle_atan(
    float v0x, float v0y, float v0z,
    float v1x, float v1y, float v1z,
    float v2x, float v2y, float v2z,
    float px, float py, float pz) {
    float ax = v0x - px, ay = v0y - py, az = v0z - pz;
    float bx = v1x - px, by = v1y - py, bz = v1z - pz;
    float cx = v2x - px, cy = v2y - py, cz = v2z - pz;

    float la = __builtin_amdgcn_sqrtf(fmaf(ax, ax, fmaf(ay, ay, az * az)));
    float lb = __builtin_amdgcn_sqrtf(fmaf(bx, bx, fmaf(by, by, bz * bz)));
    float lc = __builtin_amdgcn_sqrtf(fmaf(cx, cx, fmaf(cy, cy, cz * cz)));

    float crx = by * cz - bz * cy;
    float cry = bz * cx - bx * cz;
    float crz = bx * cy - by * cx;
    float det = ax * crx + ay * cry + az * crz;

    float dab = fmaf(ax, bx, fmaf(ay, by, az * bz));
    float dbc = fmaf(bx, cx, fmaf(by, cy, bz * cz));
    float dca = fmaf(cx, ax, fmaf(cy, ay, cz * az));
    float den = fmaf(la * lb, lc, fmaf(dab, lc, fmaf(dbc, la, dca * lb)));

    return fast_atan2f(det, den);
}

// ---------------------------------------------------------------------------
// SINGLE fused kernel. grid = B * (P/PPB) blocks, 256 threads.
// Phase 1: waves 0/1 compute band0/band1 means into LDS (identical reduction
//          order to the previous gather kernel -> bit-identical bands).
// Phase 2: all threads stride faces (8 each), gathering vertices directly
//          from verts/faces with band substitution; accumulate PPB points.
// Phase 3: shfl + LDS block reduction, write out. No workspace used.
// ---------------------------------------------------------------------------
__global__ __launch_bounds__(256) void winding_fused_kernel(
    const float* __restrict__ verts,  // [B][V][3]
    const int* __restrict__ vidx,     // [P]
    const int* __restrict__ b0i,      // [LB]
    const int* __restrict__ b1i,      // [LB]
    const int* __restrict__ faces,    // [F][3]
    float* __restrict__ out,          // [B][P]
    int P, int F, int V, int LB) {
    int nPB = (P + PPB - 1) / PPB;
    int b  = blockIdx.x / nPB;
    int pb = blockIdx.x - b * nPB;
    int p0 = pb * PPB;
    int tid = threadIdx.x;
    int wid = tid >> 6, lane = tid & 63;

    // ---- Phase 1: band means (waves 0 and 1) ----
    __shared__ float sband[6];
    if (wid < 2) {
        const int* bi = wid ? b1i : b0i;
        float sx = 0.f, sy = 0.f, sz = 0.f;
        for (int i = lane; i < LB; i += 64) {
            int vi = bi[i];
            const float* q = verts + ((size_t)b * V + vi) * 3;
            sx += q[0]; sy += q[1]; sz += q[2];
        }
#pragma unroll
        for (int off = 32; off; off >>= 1) {
            sx += __shfl_down(sx, off, 64);
            sy += __shfl_down(sy, off, 64);
            sz += __shfl_down(sz, off, 64);
        }
        if (lane == 0) {
            float inv = 1.0f / (float)LB;
            sband[wid * 3 + 0] = sx * inv;
            sband[wid * 3 + 1] = sy * inv;
            sband[wid * 3 + 2] = sz * inv;
        }
    }
    __syncthreads();

    float bnd[6];
#pragma unroll
    for (int c = 0; c < 6; ++c) bnd[c] = sband[c];

    // ---- Phase 2: points (broadcast loads) + face loop ----
    float px[PPB], py[PPB], pz[PPB], acc[PPB];
#pragma unroll
    for (int j = 0; j < PPB; ++j) {
        int p = (p0 + j < P) ? (p0 + j) : (P - 1);
        const float* pt = verts + ((size_t)b * V + vidx[p]) * 3;
        px[j] = pt[0]; py[j] = pt[1]; pz[j] = pt[2];
        acc[j] = 0.f;
    }

    const float* vb = verts + (size_t)b * V * 3;
    for (int f = tid; f < F; f += 256) {
        int i0 = faces[f * 3 + 0];
        int i1 = faces[f * 3 + 1];
        int i2 = faces[f * 3 + 2];
        float v0x, v0y, v0z, v1x, v1y, v1z, v2x, v2y, v2z;
        if (i0 < V) { const float* s = vb + (size_t)i0 * 3; v0x = s[0]; v0y = s[1]; v0z = s[2]; }
        else { int j = (i0 - V) * 3; v0x = bnd[j]; v0y = bnd[j + 1]; v0z = bnd[j + 2]; }
        if (i1 < V) { const float* s = vb + (size_t)i1 * 3; v1x = s[0]; v1y = s[1]; v1z = s[2]; }
        else { int j = (i1 - V) * 3; v1x = bnd[j]; v1y = bnd[j + 1]; v1z = bnd[j + 2]; }
        if (i2 < V) { const float* s = vb + (size_t)i2 * 3; v2x = s[0]; v2y = s[1]; v2z = s[2]; }
        else { int j = (i2 - V) * 3; v2x = bnd[j]; v2y = bnd[j + 1]; v2z = bnd[j + 2]; }

#pragma unroll
        for (int j = 0; j < PPB; ++j) {
            acc[j] += solid_angle_atan(v0x, v0y, v0z, v1x, v1y, v1z,
                                       v2x, v2y, v2z, px[j], py[j], pz[j]);
        }
    }

    // ---- Phase 3: block reduction ----
#pragma unroll
    for (int off = 32; off; off >>= 1) {
#pragma unroll
        for (int j = 0; j < PPB; ++j) acc[j] += __shfl_down(acc[j], off, 64);
    }

    __shared__ float part[4][PPB];
    if ((tid & 63) == 0) {
#pragma unroll
        for (int j = 0; j < PPB; ++j) part[wid][j] = acc[j];
    }
    __syncthreads();
    if (tid < PPB) {
        int p = p0 + tid;
        if (p < P) {
            float tot = part[0][tid] + part[1][tid] + part[2][tid] + part[3][tid];
            out[(size_t)b * P + p] = tot * INV_TWO_PI;
        }
    }
}

extern "C" void kernel_launch(void* const* d_in, const int* in_sizes, int n_in,
                              void* d_out, int out_size, void* d_ws, size_t ws_size,
                              hipStream_t stream) {
    const float* verts = (const float*)d_in[0];
    const int* svidx   = (const int*)d_in[1];
    const int* b0i     = (const int*)d_in[2];
    const int* b1i     = (const int*)d_in[3];
    const int* faces   = (const int*)d_in[4];
    float* out = (float*)d_out;

    int P  = in_sizes[1];
    int LB = in_sizes[2];
    int F  = in_sizes[4] / 3;
    int B  = out_size / P;
    int V  = in_sizes[0] / (3 * B);

    int nPB = (P + PPB - 1) / PPB;
    winding_fused_kernel<<<B * nPB, 256, 0, stream>>>(verts, svidx, b0i, b1i,
                                                      faces, out, P, F, V, LB);
    (void)d_ws; (void)ws_size; (void)n_in;
}

// Round 9
// 81.021 us; speedup vs baseline: 1.0913x; 1.0913x over previous
//
#include <hip/hip_runtime.h>
#include <math.h>

#define INV_TWO_PI 0.15915494309189535f

// ---------------------------------------------------------------------------
// fast atan2: degree-15 odd minimax on [0,1] + quadrant fixup.
// Branch-cut semantics match numpy: atan2(+-0, neg) = +-pi, atan2(0,0)=0.
// ---------------------------------------------------------------------------
__device__ __forceinline__ float fast_atan2f(float y, float x) {
    const float PI   = 3.14159265358979f;
    const float PI_2 = 1.57079632679490f;
    float ax = fabsf(x), ay = fabsf(y);
    float mx = fmaxf(ax, ay), mn = fminf(ax, ay);
    float inv = __builtin_amdgcn_rcpf(mx);
    float t = (mx > 0.f) ? mn * inv : 0.f;   // guard 0/0
    float s = t * t;
    float r = -0.0040540580f;
    r = fmaf(r, s, 0.0218612288f);
    r = fmaf(r, s, -0.0559098861f);
    r = fmaf(r, s, 0.0964200441f);
    r = fmaf(r, s, -0.1390853351f);
    r = fmaf(r, s, 0.1994653599f);
    r = fmaf(r, s, -0.3332985605f);
    r = fmaf(r, s, 0.9999993329f);
    r = r * t;
    if (ay > ax) r = PI_2 - r;
    if (x < 0.f) r = PI - r;
    return copysignf(r, y);
}

// det = a.(b x c) computed directly so p == vertex gives det = 0, den = 0
// exactly (matches numpy reference; absmax == 0.0 verified rounds 3/6/7/8).
__device__ __forceinline__ float solid_angle_atan(
    float v0x, float v0y, float v0z,
    float v1x, float v1y, float v1z,
    float v2x, float v2y, float v2z,
    float px, float py, float pz) {
    float ax = v0x - px, ay = v0y - py, az = v0z - pz;
    float bx = v1x - px, by = v1y - py, bz = v1z - pz;
    float cx = v2x - px, cy = v2y - py, cz = v2z - pz;

    float la = __builtin_amdgcn_sqrtf(fmaf(ax, ax, fmaf(ay, ay, az * az)));
    float lb = __builtin_amdgcn_sqrtf(fmaf(bx, bx, fmaf(by, by, bz * bz)));
    float lc = __builtin_amdgcn_sqrtf(fmaf(cx, cx, fmaf(cy, cy, cz * cz)));

    float crx = by * cz - bz * cy;
    float cry = bz * cx - bx * cz;
    float crz = bx * cy - by * cx;
    float det = ax * crx + ay * cry + az * crz;

    float dab = fmaf(ax, bx, fmaf(ay, by, az * bz));
    float dbc = fmaf(bx, cx, fmaf(by, cy, bz * cz));
    float dca = fmaf(cx, ax, fmaf(cy, ay, cz * az));
    float den = fmaf(la * lb, lc, fmaf(dab, lc, fmaf(dbc, la, dca * lb)));

    return fast_atan2f(det, den);
}

// ---------------------------------------------------------------------------
// Kernel 1: fused band-means + triangle gather (v5 structure, unchanged).
// ---------------------------------------------------------------------------
__global__ void gather_tris_kernel(const float* __restrict__ verts,
                                   const int* __restrict__ b0i,
                                   const int* __restrict__ b1i,
                                   const int* __restrict__ faces,   // [F][3]
                                   float* __restrict__ tri,         // [B][F][12]
                                   int B, int V, int F, int LB, int nfc) {
    int b  = blockIdx.x / nfc;
    int fc = blockIdx.x - b * nfc;
    int tid = threadIdx.x;
    int wid = tid >> 6, lane = tid & 63;

    __shared__ float sband[6];
    if (wid < 2) {
        const int* bi = wid ? b1i : b0i;
        float sx = 0.f, sy = 0.f, sz = 0.f;
        for (int i = lane; i < LB; i += 64) {
            int vi = bi[i];
            const float* q = verts + ((size_t)b * V + vi) * 3;
            sx += q[0]; sy += q[1]; sz += q[2];
        }
#pragma unroll
        for (int off = 32; off; off >>= 1) {
            sx += __shfl_down(sx, off, 64);
            sy += __shfl_down(sy, off, 64);
            sz += __shfl_down(sz, off, 64);
        }
        if (lane == 0) {
            float inv = 1.0f / (float)LB;
            sband[wid * 3 + 0] = sx * inv;
            sband[wid * 3 + 1] = sy * inv;
            sband[wid * 3 + 2] = sz * inv;
        }
    }
    __syncthreads();

    int f = fc * 256 + tid;
    if (f >= F) return;

    int i0 = faces[f * 3 + 0];
    int i1 = faces[f * 3 + 1];
    int i2 = faces[f * 3 + 2];
    float v0x, v0y, v0z, v1x, v1y, v1z, v2x, v2y, v2z;
    if (i0 < V) { const float* s = verts + ((size_t)b * V + i0) * 3; v0x = s[0]; v0y = s[1]; v0z = s[2]; }
    else { int j = (i0 - V) * 3; v0x = sband[j]; v0y = sband[j + 1]; v0z = sband[j + 2]; }
    if (i1 < V) { const float* s = verts + ((size_t)b * V + i1) * 3; v1x = s[0]; v1y = s[1]; v1z = s[2]; }
    else { int j = (i1 - V) * 3; v1x = sband[j]; v1y = sband[j + 1]; v1z = sband[j + 2]; }
    if (i2 < V) { const float* s = verts + ((size_t)b * V + i2) * 3; v2x = s[0]; v2y = s[1]; v2z = s[2]; }
    else { int j = (i2 - V) * 3; v2x = sband[j]; v2y = sband[j + 1]; v2z = sband[j + 2]; }

    float4* d = (float4*)(tri + ((size_t)b * F + f) * 12);
    d[0] = make_float4(v0x, v0y, v0z, v1x);
    d[1] = make_float4(v1y, v1z, v2x, v2y);
    d[2] = make_float4(v2z, 0.f, 0.f, 0.f);
}

// ---------------------------------------------------------------------------
// Kernel 2 (main): 4 points per 256-thread block, EXPLICIT SCALARS ONLY —
// no px[]/acc[] arrays (rule #20: runtime-indexed arrays -> scratch; round-8
// profile showed VGPR=32 + anomalous writes = scratch signature).
// ---------------------------------------------------------------------------
__global__ __launch_bounds__(256) void winding4_kernel(
    const float* __restrict__ tri,    // [B][F][12]
    const float* __restrict__ verts,  // [B][V][3]
    const int* __restrict__ vidx,     // [P]
    float* __restrict__ out,          // [B][P]
    int P, int F, int V) {
    int nPB = (P + 3) / 4;
    int b  = blockIdx.x / nPB;
    int pb = blockIdx.x - b * nPB;
    int p0 = pb * 4;
    int tid = threadIdx.x;

    const float4* tb = (const float4*)(tri + (size_t)b * F * 12);

    int f = tid;
    float4 q0 = make_float4(0.f, 0.f, 0.f, 0.f), q1 = q0, q2 = q0;
    if (f < F) {
        q0 = tb[(size_t)f * 3 + 0];
        q1 = tb[(size_t)f * 3 + 1];
        q2 = tb[(size_t)f * 3 + 2];
    }

    const float* vbase = verts + (size_t)b * V * 3;
    int pc0 = (p0 + 0 < P) ? (p0 + 0) : (P - 1);
    int pc1 = (p0 + 1 < P) ? (p0 + 1) : (P - 1);
    int pc2 = (p0 + 2 < P) ? (p0 + 2) : (P - 1);
    int pc3 = (p0 + 3 < P) ? (p0 + 3) : (P - 1);
    const float* pt0 = vbase + (size_t)vidx[pc0] * 3;
    const float* pt1 = vbase + (size_t)vidx[pc1] * 3;
    const float* pt2 = vbase + (size_t)vidx[pc2] * 3;
    const float* pt3 = vbase + (size_t)vidx[pc3] * 3;
    float px0 = pt0[0], py0 = pt0[1], pz0 = pt0[2];
    float px1 = pt1[0], py1 = pt1[1], pz1 = pt1[2];
    float px2 = pt2[0], py2 = pt2[1], pz2 = pt2[2];
    float px3 = pt3[0], py3 = pt3[1], pz3 = pt3[2];
    float acc0 = 0.f, acc1 = 0.f, acc2 = 0.f, acc3 = 0.f;

    while (f < F) {
        int fn = f + 256;
        float4 n0 = q0, n1 = q1, n2 = q2;
        if (fn < F) {
            n0 = tb[(size_t)fn * 3 + 0];
            n1 = tb[(size_t)fn * 3 + 1];
            n2 = tb[(size_t)fn * 3 + 2];
        }
        acc0 += solid_angle_atan(q0.x, q0.y, q0.z, q0.w, q1.x, q1.y,
                                 q1.z, q1.w, q2.x, px0, py0, pz0);
        acc1 += solid_angle_atan(q0.x, q0.y, q0.z, q0.w, q1.x, q1.y,
                                 q1.z, q1.w, q2.x, px1, py1, pz1);
        acc2 += solid_angle_atan(q0.x, q0.y, q0.z, q0.w, q1.x, q1.y,
                                 q1.z, q1.w, q2.x, px2, py2, pz2);
        acc3 += solid_angle_atan(q0.x, q0.y, q0.z, q0.w, q1.x, q1.y,
                                 q1.z, q1.w, q2.x, px3, py3, pz3);
        q0 = n0; q1 = n1; q2 = n2;
        f = fn;
    }

#pragma unroll
    for (int off = 32; off; off >>= 1) {
        acc0 += __shfl_down(acc0, off, 64);
        acc1 += __shfl_down(acc1, off, 64);
        acc2 += __shfl_down(acc2, off, 64);
        acc3 += __shfl_down(acc3, off, 64);
    }

    __shared__ float part0[4], part1[4], part2[4], part3[4];
    int wid = tid >> 6;
    if ((tid & 63) == 0) {
        part0[wid] = acc0;
        part1[wid] = acc1;
        part2[wid] = acc2;
        part3[wid] = acc3;
    }
    __syncthreads();
    if (tid == 0) {
        float t0 = part0[0] + part0[1] + part0[2] + part0[3];
        float t1 = part1[0] + part1[1] + part1[2] + part1[3];
        float t2 = part2[0] + part2[1] + part2[2] + part2[3];
        float t3 = part3[0] + part3[1] + part3[2] + part3[3];
        float* o = out + (size_t)b * P + p0;
        if (p0 + 0 < P) o[0] = t0 * INV_TWO_PI;
        if (p0 + 1 < P) o[1] = t1 * INV_TWO_PI;
        if (p0 + 2 < P) o[2] = t2 * INV_TWO_PI;
        if (p0 + 3 < P) o[3] = t3 * INV_TWO_PI;
    }
}

extern "C" void kernel_launch(void* const* d_in, const int* in_sizes, int n_in,
                              void* d_out, int out_size, void* d_ws, size_t ws_size,
                              hipStream_t stream) {
    const float* verts = (const float*)d_in[0];
    const int* svidx   = (const int*)d_in[1];
    const int* b0i     = (const int*)d_in[2];
    const int* b1i     = (const int*)d_in[3];
    const int* faces   = (const int*)d_in[4];
    float* out = (float*)d_out;

    int P  = in_sizes[1];
    int LB = in_sizes[2];
    int F  = in_sizes[4] / 3;
    int B  = out_size / P;
    int V  = in_sizes[0] / (3 * B);

    float* tri = (float*)d_ws;   // B*F*12 floats (ws is 256MB, ample)
    int nfc = (F + 255) / 256;
    gather_tris_kernel<<<B * nfc, 256, 0, stream>>>(verts, b0i, b1i, faces,
                                                    tri, B, V, F, LB, nfc);
    int nPB = (P + 3) / 4;
    winding4_kernel<<<B * nPB, 256, 0, stream>>>(tri, verts, svidx, out, P, F, V);
}